// Round 12
// baseline (192.700 us; speedup 1.0000x reference)
//
#include <hip/hip_runtime.h>
#include <hip/hip_fp16.h>
#include <stdint.h>

// GCN: x[N,8] -> GCNConv(8,64)+ReLU -> GCNConv(64,12)+ReLU -> segment_max(G) -> @Wl+bl -> log_softmax
// N=200000, E=1600000, G=2000. fp32 params; indices int32.
//
// R12: node-per-LANE aggregation (vs R10's 4 nodes/wave). Each lane: 4
// coalesced pad loads -> 17 independent row-gathers (16B) -> in-lane fp32
// accumulate (zero shfl). k_agg1f fuses the whole 8->64->12 MLP per-lane
// (weights LDS-broadcast, 1280 FMA @ full lane util) -> z1 buffer and one
// launch eliminated. k_agg2 same per-lane pattern, 34 gathers. CSR build
// (binA/binB) unchanged from R11.
// Algebra (R3): xd=x*dis ; z[t]=dis[t]*(xd[t]+sum xd[src]) ;
// y2=(relu(z@W1+b1)@W2)*dis ; h2[t]=relu(dis[t]*(y2[t]+sum y2[src])+b2) ;
// pool-max per graph (fused head).

constexpr int IN_DIM = 8;
constexpr int H1 = 64;
constexpr int H2 = 12;
constexpr int NPB = 512;      // nodes per bucket (bucket = dst >> 9)
constexpr int NBK = 391;      // ceil(200000 / 512)
constexpr int CAP = 4608;     // per-bucket capacity (avg 4096, sd ~64)
constexpr int CHUNK = 4096;   // edges per binA block
constexpr int SLOTS = 16;     // padded csr slots per node

typedef float nfloat4 __attribute__((ext_vector_type(4)));
__device__ __forceinline__ void nt_store_f4(void* p, float4 v) {
    nfloat4 w = {v.x, v.y, v.z, v.w};
    __builtin_nontemporal_store(w, (nfloat4*)p);
}

__device__ __forceinline__ void acc_row8(float* acc, int4 rv) {
    const __half2* h = (const __half2*)&rv;
#pragma unroll
    for (int q = 0; q < 4; ++q) {
        float2 f = __half22float2(h[q]);
        acc[2 * q] += f.x; acc[2 * q + 1] += f.y;
    }
}

// ---------------- pass A: bin edges into bucket regions (uint32 records) ----------------
__global__ void k_binA(const int* __restrict__ src, const int* __restrict__ dst,
                       uint32_t* __restrict__ pairs, int* __restrict__ bcursor, int ne) {
    __shared__ int s_cur[NBK];
    __shared__ int s_gb[NBK];
    for (int i = threadIdx.x; i < NBK; i += 256) s_cur[i] = 0;
    __syncthreads();
    int e0 = blockIdx.x * CHUNK;
    int rec[16];
#pragma unroll
    for (int i = 0; i < 16; ++i) {
        int e = e0 + i * 256 + threadIdx.x;
        rec[i] = -1;
        if (e < ne) {
            int d = __builtin_nontemporal_load(&dst[e]);
            int b = d >> 9;
            int off = atomicAdd(&s_cur[b], 1);            // off < CHUNK (12 bits)
            rec[i] = (off << 18) | ((d & 511) << 9) | b;  // 12|9|9 bits
        }
    }
    __syncthreads();
    for (int b = threadIdx.x; b < NBK; b += 256) {
        int c = s_cur[b];
        s_gb[b] = (c > 0) ? atomicAdd(&bcursor[b], c) : 0;
    }
    __syncthreads();
#pragma unroll
    for (int i = 0; i < 16; ++i) {
        if (rec[i] < 0) continue;
        int e = e0 + i * 256 + threadIdx.x;
        int b = rec[i] & 511;
        int dl = (rec[i] >> 9) & 511;
        int off = (rec[i] >> 18) + s_gb[b];
        if (off < CAP)
            pairs[(size_t)b * CAP + off] =
                ((uint32_t)dl << 18) | (uint32_t)__builtin_nontemporal_load(&src[e]);
    }
}

// ---------------- pass B: per-bucket counting sort -> PADDED csr + meta/dis/xdh ----------
__global__ void __launch_bounds__(256) k_binB(
        const uint32_t* __restrict__ pairs, const int* __restrict__ bcursor,
        const float* __restrict__ x, int* __restrict__ csr_pad,
        int* __restrict__ csr_ovf, unsigned int* __restrict__ meta,
        float* __restrict__ dis, __half2* __restrict__ xdh, int n) {
    __shared__ int s_hist[NPB];
    __shared__ int s_start[NPB];
    __shared__ int s_cur[NPB];
    __shared__ int s_tmp[256];
    __shared__ int s_pad[NPB * SLOTS];   // 32 KB padded image
    int b = blockIdx.x;
    int t = threadIdx.x;
    int cnt = min(bcursor[b], CAP);
    const uint32_t* pb = pairs + (size_t)b * CAP;
    for (int i = t; i < NPB; i += 256) { s_hist[i] = 0; s_cur[i] = 0; }
    for (int i = t; i < NPB * SLOTS; i += 256) s_pad[i] = n;   // dummy fill
    __syncthreads();
    for (int i = t; i < cnt; i += 256)
        atomicAdd(&s_hist[__builtin_nontemporal_load(&pb[i]) >> 18], 1);
    __syncthreads();
    // exclusive scan of s_hist[512] with 256 threads (2 elems each)
    int b2i = t * 2;
    int v0 = s_hist[b2i], v1 = s_hist[b2i + 1];
    int tot = v0 + v1;
    s_tmp[t] = tot;
    __syncthreads();
    for (int off = 1; off < 256; off <<= 1) {
        int u = (t >= off) ? s_tmp[t - off] : 0;
        __syncthreads();
        s_tmp[t] += u;
        __syncthreads();
    }
    int ex = s_tmp[t] - tot;
    s_start[b2i] = ex;
    s_start[b2i + 1] = ex + v0;
    __syncthreads();
    int cb = b * CAP;                    // bucket-strided overflow base
    int node0 = b << 9;
    for (int i = t; i < NPB; i += 256) {
        int node = node0 + i;
        if (node < n) {
            meta[node] = ((unsigned int)s_hist[i] << 21) | (unsigned int)(cb + s_start[i]);
            float di = rsqrtf((float)(s_hist[i] + 1));   // +1 self-loop
            dis[node] = di;
            const float4* xi = (const float4*)(x + (size_t)node * IN_DIM);
            float4 a = xi[0], c = xi[1];
            union { __half2 h[4]; int iv[4]; } u;
            u.h[0] = __float22half2_rn(make_float2(a.x * di, a.y * di));
            u.h[1] = __float22half2_rn(make_float2(a.z * di, a.w * di));
            u.h[2] = __float22half2_rn(make_float2(c.x * di, c.y * di));
            u.h[3] = __float22half2_rn(make_float2(c.z * di, c.w * di));
            ((int4*)xdh)[node] = make_int4(u.iv[0], u.iv[1], u.iv[2], u.iv[3]);
        } else if (node == n) {
            ((int4*)xdh)[n] = make_int4(0, 0, 0, 0);     // dummy zero row
        }
    }
    __syncthreads();
    // place: first 16 per node into LDS pad; overflow -> bucket-strided csr_ovf (rare)
    for (int i = t; i < cnt; i += 256) {
        uint32_t p = __builtin_nontemporal_load(&pb[i]);
        int dl = p >> 18;
        int sidx = (int)(p & 0x3FFFFu);
        int pos = atomicAdd(&s_cur[dl], 1);
        if (pos < SLOTS) s_pad[dl * SLOTS + pos] = sidx;
        else             csr_ovf[cb + s_start[dl] + pos] = sidx;
    }
    __syncthreads();
    // coalesced int4 flush of padded image (guard phantom nodes past n)
    for (int i = t; i < NPB * SLOTS / 4; i += 256) {
        int node = node0 + (i >> 2);
        if (node < n)
            ((int4*)csr_pad)[(size_t)node0 * 4 + i] = ((int4*)s_pad)[i];
    }
}

// ---------------- agg1 + MLP fused: node per LANE ----------------
// lane: 4 pad loads -> 17 independent 16B gathers -> in-lane fp32 sum -> 8->64->12 MLP
__global__ void __launch_bounds__(256) k_agg1f(
        const int* __restrict__ csr_pad, const int* __restrict__ csr_ovf,
        const unsigned int* __restrict__ meta, const __half2* __restrict__ xdh,
        const float* __restrict__ dis, const float* __restrict__ W1,
        const float* __restrict__ b1, const float* __restrict__ W2,
        __half2* __restrict__ y2h, int n) {
    __shared__ float sW1[IN_DIM * H1];   // [k][d] row-major
    __shared__ float sW2[H1 * H2];       // [d][j]
    __shared__ float sb1[H1];
    for (int i = threadIdx.x; i < IN_DIM * H1; i += 256) sW1[i] = W1[i];
    for (int i = threadIdx.x; i < H1 * H2; i += 256) sW2[i] = W2[i];
    if (threadIdx.x < H1) sb1[threadIdx.x] = b1[threadIdx.x];
    __syncthreads();
    int node = blockIdx.x * 256 + threadIdx.x;
    if (node > n) return;
    int4* orow = (int4*)y2h + (size_t)node * 2;
    if (node == n) {                     // dummy zero row for agg2
        orow[0] = make_int4(0, 0, 0, 0);
        orow[1] = make_int4(0, 0, 0, 0);
        return;
    }
    const int4* pr = (const int4*)(csr_pad + (size_t)node * SLOTS);
    int4 p0 = pr[0], p1 = pr[1], p2 = pr[2], p3 = pr[3];
    unsigned int m = meta[node];
    const int4* xt = (const int4*)xdh;   // 16B rows

    float acc[8] = {0, 0, 0, 0, 0, 0, 0, 0};
    int idx[16] = {p0.x, p0.y, p0.z, p0.w, p1.x, p1.y, p1.z, p1.w,
                   p2.x, p2.y, p2.z, p2.w, p3.x, p3.y, p3.z, p3.w};
    acc_row8(acc, xt[node]);             // self-loop
#pragma unroll
    for (int i = 0; i < 16; ++i) acc_row8(acc, xt[(size_t)idx[i]]);
    int deg = m >> 21;
    if (deg > SLOTS) {                   // rare overflow (~0.4% of nodes)
        int r0 = (int)(m & 0x1FFFFF);
        for (int r = SLOTS; r < deg; ++r) acc_row8(acc, xt[(size_t)csr_ovf[r0 + r]]);
    }
    float di = dis[node];
    float z[8];
#pragma unroll
    for (int k = 0; k < 8; ++k) z[k] = acc[k] * di;

    // MLP: y2[j] = sum_d relu(sum_k z[k]*W1[k][d] + b1[d]) * W2[d][j]
    float y2[H2];
#pragma unroll
    for (int j = 0; j < H2; ++j) y2[j] = 0.f;
    for (int d = 0; d < H1; ++d) {
        float h = sb1[d];
#pragma unroll
        for (int k = 0; k < 8; ++k) h = fmaf(z[k], sW1[k * H1 + d], h);
        h = fmaxf(h, 0.f);
#pragma unroll
        for (int j = 0; j < H2; ++j) y2[j] = fmaf(h, sW2[d * H2 + j], y2[j]);
    }
    union { __half2 h2v[8]; int iv[8]; } u;
#pragma unroll
    for (int q = 0; q < 6; ++q)
        u.h2v[q] = __float22half2_rn(make_float2(y2[2 * q] * di, y2[2 * q + 1] * di));
    u.h2v[6] = __float22half2_rn(make_float2(0.f, 0.f));
    u.h2v[7] = u.h2v[6];
    orow[0] = make_int4(u.iv[0], u.iv[1], u.iv[2], u.iv[3]);
    orow[1] = make_int4(u.iv[4], u.iv[5], u.iv[6], u.iv[7]);
}

// ---------------- layer-2 aggregation: node per LANE, 34 independent gathers ----------
__global__ void __launch_bounds__(256) k_agg2(
        const int* __restrict__ csr_pad, const int* __restrict__ csr_ovf,
        const unsigned int* __restrict__ meta, const __half2* __restrict__ y2h,
        const float* __restrict__ dis, const float* __restrict__ b2,
        float* __restrict__ h2, int n) {
    int node = blockIdx.x * 256 + threadIdx.x;
    if (node >= n) return;
    const int4* pr = (const int4*)(csr_pad + (size_t)node * SLOTS);
    int4 p0 = pr[0], p1 = pr[1], p2 = pr[2], p3 = pr[3];
    unsigned int m = meta[node];
    const int4* yt = (const int4*)y2h;   // 32B rows = 2 int4

    float acc[12] = {0, 0, 0, 0, 0, 0, 0, 0, 0, 0, 0, 0};
    auto addrow = [&](int nb) {
        int4 ra = yt[(size_t)nb * 2];
        int4 rb = yt[(size_t)nb * 2 + 1];
        const __half2* ha = (const __half2*)&ra;
        const __half2* hb = (const __half2*)&rb;
#pragma unroll
        for (int q = 0; q < 4; ++q) {
            float2 f = __half22float2(ha[q]);
            acc[2 * q] += f.x; acc[2 * q + 1] += f.y;
        }
#pragma unroll
        for (int q = 0; q < 2; ++q) {
            float2 f = __half22float2(hb[q]);
            acc[8 + 2 * q] += f.x; acc[9 + 2 * q] += f.y;
        }
    };
    int idx[16] = {p0.x, p0.y, p0.z, p0.w, p1.x, p1.y, p1.z, p1.w,
                   p2.x, p2.y, p2.z, p2.w, p3.x, p3.y, p3.z, p3.w};
    addrow(node);                        // self-loop
#pragma unroll
    for (int i = 0; i < 16; ++i) addrow(idx[i]);
    int deg = m >> 21;
    if (deg > SLOTS) {                   // rare overflow
        int r0 = (int)(m & 0x1FFFFF);
        for (int r = SLOTS; r < deg; ++r) addrow(csr_ovf[r0 + r]);
    }
    float di = dis[node];
    float4 v0, v1, v2;
    v0.x = fmaxf(fmaf(acc[0], di, b2[0]), 0.f);
    v0.y = fmaxf(fmaf(acc[1], di, b2[1]), 0.f);
    v0.z = fmaxf(fmaf(acc[2], di, b2[2]), 0.f);
    v0.w = fmaxf(fmaf(acc[3], di, b2[3]), 0.f);
    v1.x = fmaxf(fmaf(acc[4], di, b2[4]), 0.f);
    v1.y = fmaxf(fmaf(acc[5], di, b2[5]), 0.f);
    v1.z = fmaxf(fmaf(acc[6], di, b2[6]), 0.f);
    v1.w = fmaxf(fmaf(acc[7], di, b2[7]), 0.f);
    v2.x = fmaxf(fmaf(acc[8], di, b2[8]), 0.f);
    v2.y = fmaxf(fmaf(acc[9], di, b2[9]), 0.f);
    v2.z = fmaxf(fmaf(acc[10], di, b2[10]), 0.f);
    v2.w = fmaxf(fmaf(acc[11], di, b2[11]), 0.f);
    float* o = h2 + (size_t)node * H2;
    nt_store_f4(o, v0);
    nt_store_f4(o + 4, v1);
    nt_store_f4(o + 8, v2);
}

// ---------------- pool (block per graph, binary-search bounds, LDS reduce) + head ----
__global__ void __launch_bounds__(128) k_pool(
        const float* __restrict__ h2, const int* __restrict__ batch,
        const float* __restrict__ Wl, const float* __restrict__ bl,
        float* __restrict__ out, int n) {
    __shared__ float s_m[120];
    __shared__ float s_p[12];
    __shared__ int s_be[2];
    int g = blockIdx.x;
    int t = threadIdx.x;
    if (t < 2) {                 // first i with batch[i] >= g+t (batch sorted)
        int target = g + t;
        int lo = 0, hi = n;
        while (lo < hi) {
            int mid = (lo + hi) >> 1;
            if (batch[mid] < target) lo = mid + 1; else hi = mid;
        }
        s_be[t] = lo;
    }
    __syncthreads();
    int gs = s_be[0], ge = s_be[1];
    if (t < 120) {
        int off = t / 12, dim = t - off * 12;
        float m = 0.f;                       // h2 >= 0
        for (int i = gs + off; i < ge; i += 10)
            m = fmaxf(m, h2[(size_t)i * 12 + dim]);
        s_m[t] = m;
    }
    __syncthreads();
    if (t < 12) {
        float m = s_m[t];
#pragma unroll
        for (int k = 1; k < 10; ++k) m = fmaxf(m, s_m[t + 12 * k]);
        s_p[t] = m;
    }
    __syncthreads();
    if (t == 0) {
        float l0 = bl[0], l1 = bl[1];
#pragma unroll
        for (int k = 0; k < H2; ++k) {
            float pv = s_p[k];
            l0 = fmaf(pv, Wl[k * 2 + 0], l0);
            l1 = fmaf(pv, Wl[k * 2 + 1], l1);
        }
        float m = fmaxf(l0, l1);
        float lse = m + logf(expf(l0 - m) + expf(l1 - m));
        out[g * 2 + 0] = l0 - lse;
        out[g * 2 + 1] = l1 - lse;
    }
}

extern "C" void kernel_launch(void* const* d_in, const int* in_sizes, int n_in,
                              void* d_out, int out_size, void* d_ws, size_t ws_size,
                              hipStream_t stream) {
    const float* x   = (const float*)d_in[0];
    const int* ei    = (const int*)d_in[1];
    const int* batch = (const int*)d_in[2];
    const float* W1  = (const float*)d_in[3];
    const float* b1  = (const float*)d_in[4];
    const float* W2  = (const float*)d_in[5];
    const float* b2  = (const float*)d_in[6];
    const float* Wl  = (const float*)d_in[7];
    const float* bl  = (const float*)d_in[8];
    float* out = (float*)d_out;

    const int N = in_sizes[0] / IN_DIM;   // 200000
    const int E = in_sizes[1] / 2;        // 1600000
    const int G = out_size / 2;           // 2000
    const int* src = ei;
    const int* dst = ei + E;

    auto cdiv = [](long long a, int b) { return (int)((a + b - 1) / b); };

    // workspace carve, 64B-aligned
    char* wp = (char*)d_ws;
    auto carve = [&](size_t bytes) {
        char* p = wp;
        wp += (bytes + 63) & ~(size_t)63;
        return p;
    };
    int*          bcursor = (int*)carve(NBK * 4);
    unsigned int* meta    = (unsigned int*)carve((size_t)N * 4);
    float*        dis     = (float*)carve((size_t)N * 4);
    __half2*      xdh     = (__half2*)carve((size_t)(N + 1) * 16);   // 16B rows
    __half2*      y2h     = (__half2*)carve((size_t)(N + 1) * 32);   // 32B rows
    float*        h2      = (float*)carve((size_t)N * H2 * 4);
    uint32_t*     pairs   = (uint32_t*)carve((size_t)NBK * CAP * 4);
    int*          csr_pad = (int*)carve((size_t)N * SLOTS * 4);
    int*          csr_ovf = (int*)carve((size_t)NBK * CAP * 4);

    (void)hipMemsetAsync(bcursor, 0, NBK * sizeof(int), stream);

    // CSR build (bucketed counting sort -> padded csr), fused with meta/dis/xdh
    k_binA<<<cdiv(E, CHUNK), 256, 0, stream>>>(src, dst, pairs, bcursor, E);
    k_binB<<<NBK, 256, 0, stream>>>(pairs, bcursor, x, csr_pad, csr_ovf,
                                    meta, dis, xdh, N);

    // fused layer-1 aggregation + MLP, layer-2 aggregation, pool+head
    k_agg1f<<<cdiv((long long)N + 1, 256), 256, 0, stream>>>(
        csr_pad, csr_ovf, meta, xdh, dis, W1, b1, W2, y2h, N);
    k_agg2<<<cdiv(N, 256), 256, 0, stream>>>(csr_pad, csr_ovf, meta, y2h, dis, b2, h2, N);
    k_pool<<<G, 128, 0, stream>>>(h2, batch, Wl, bl, out, N);
}

// Round 13
// 175.167 us; speedup vs baseline: 1.1001x; 1.1001x over previous
//
#include <hip/hip_runtime.h>
#include <hip/hip_fp16.h>
#include <stdint.h>

// GCN: x[N,8] -> GCNConv(8,64)+ReLU -> GCNConv(64,12)+ReLU -> segment_max(G) -> @Wl+bl -> log_softmax
// N=200000, E=1600000, G=2000. fp32 params; indices int32.
//
// R13: CSR-build attack. binA stages pairs in a block-local bucket-SORTED LDS
// image -> flush is run-coalesced (R12 binA scattered 1 line/lane/store).
// binB at NPB=256: 782 balanced blocks, ~20KB LDS, 8 blocks/CU. Pool fused
// into agg2 via wave segmented max-scan over batch-sorted nodes (+ global
// atomicMax per segment) -> h2 buffer (19.2MB traffic) and k_pool deleted.
// Algebra (R3): xd=x*dis ; z[t]=dis[t]*(xd[t]+sum xd[src]) ;
// y2=(relu(z@W1+b1)@W2)*dis ; h2[t]=relu(dis[t]*(y2[t]+sum y2[src])+b2) ;
// pool-max per graph ; head.

constexpr int IN_DIM = 8;
constexpr int H1 = 64;
constexpr int H2 = 12;
constexpr int NPB = 256;      // nodes per bucket (bucket = dst >> 8)
constexpr int NBK = 782;      // ceil(200000 / 256)
constexpr int CAP = 2560;     // per-bucket capacity (avg 2048, sd ~45 -> 11 sigma)
constexpr int CHUNK = 4096;   // edges per binA block
constexpr int SLOTS = 16;     // padded csr slots per node

__device__ __forceinline__ void acc_row8(float* acc, int4 rv) {
    const __half2* h = (const __half2*)&rv;
#pragma unroll
    for (int q = 0; q < 4; ++q) {
        float2 f = __half22float2(h[q]);
        acc[2 * q] += f.x; acc[2 * q + 1] += f.y;
    }
}

// ---------------- pass A: bucket-sorted staging -> run-coalesced pair writes ----------
__global__ void __launch_bounds__(256) k_binA(
        const int* __restrict__ src, const int* __restrict__ dst,
        uint32_t* __restrict__ pairs, int* __restrict__ bcursor, int ne) {
    __shared__ int s_cnt[NBK];        // per-bucket count
    __shared__ int s_start[NBK];      // block-local exclusive starts
    __shared__ int s_gb[NBK];         // global run base
    __shared__ int s_tmp[256];
    __shared__ uint32_t s_img[CHUNK]; // bucket-sorted pairs (16 KB)
    __shared__ uint16_t s_bkt[CHUNK]; // bucket id per slot (8 KB)
    int t = threadIdx.x;
    for (int i = t; i < NBK; i += 256) s_cnt[i] = 0;
    __syncthreads();
    int e0 = blockIdx.x * CHUNK;
    int cntblk = min(CHUNK, ne - e0);
    int rec[16];
#pragma unroll
    for (int i = 0; i < 16; ++i) {
        int e = e0 + i * 256 + t;
        rec[i] = -1;
        if (e < ne) {
            int d = __builtin_nontemporal_load(&dst[e]);
            int b = d >> 8;                                  // 10 bits
            int off = atomicAdd(&s_cnt[b], 1);               // 12 bits
            rec[i] = (off << 18) | ((d & 255) << 10) | b;    // 12|8|10
        }
    }
    __syncthreads();
    // exclusive scan of s_cnt[782] (pad to 1024), 4 elems/thread
    int b4 = t * 4;
    int v0 = (b4 < NBK) ? s_cnt[b4] : 0;
    int v1 = (b4 + 1 < NBK) ? s_cnt[b4 + 1] : 0;
    int v2 = (b4 + 2 < NBK) ? s_cnt[b4 + 2] : 0;
    int v3 = (b4 + 3 < NBK) ? s_cnt[b4 + 3] : 0;
    int p1 = v0, p2 = v0 + v1, p3 = v0 + v1 + v2, tot = p3 + v3;
    s_tmp[t] = tot;
    __syncthreads();
    for (int off = 1; off < 256; off <<= 1) {
        int u = (t >= off) ? s_tmp[t - off] : 0;
        __syncthreads();
        s_tmp[t] += u;
        __syncthreads();
    }
    int ex = s_tmp[t] - tot;
    if (b4 < NBK)     s_start[b4] = ex;
    if (b4 + 1 < NBK) s_start[b4 + 1] = ex + p1;
    if (b4 + 2 < NBK) s_start[b4 + 2] = ex + p2;
    if (b4 + 3 < NBK) s_start[b4 + 3] = ex + p3;
    // reserve global runs
    for (int b = t; b < NBK; b += 256) {
        int c = s_cnt[b];
        s_gb[b] = (c > 0) ? atomicAdd(&bcursor[b], c) : 0;
    }
    __syncthreads();
    // place into sorted LDS image
#pragma unroll
    for (int i = 0; i < 16; ++i) {
        if (rec[i] < 0) continue;
        int e = e0 + i * 256 + t;
        int b = rec[i] & 1023;
        int dl = (rec[i] >> 10) & 255;
        int off = rec[i] >> 18;
        int pos = s_start[b] + off;
        s_img[pos] = ((uint32_t)dl << 18) | (uint32_t)__builtin_nontemporal_load(&src[e]);
        s_bkt[pos] = (uint16_t)b;
    }
    __syncthreads();
    // run-coalesced flush (consecutive i in a bucket -> consecutive global addrs)
    for (int i = t; i < cntblk; i += 256) {
        int b = s_bkt[i];
        int goff = s_gb[b] + (i - s_start[b]);
        if (goff < CAP) pairs[(size_t)b * CAP + goff] = s_img[i];
    }
}

// ---------------- pass B: per-bucket counting sort -> PADDED csr + meta/dis/xdh ----------
__global__ void __launch_bounds__(256) k_binB(
        const uint32_t* __restrict__ pairs, const int* __restrict__ bcursor,
        const float* __restrict__ x, int* __restrict__ csr_pad,
        int* __restrict__ csr_ovf, unsigned int* __restrict__ meta,
        float* __restrict__ dis, __half2* __restrict__ xdh, int n) {
    __shared__ int s_hist[NPB];
    __shared__ int s_start[NPB];
    __shared__ int s_cur[NPB];
    __shared__ int s_tmp[256];
    __shared__ int s_pad[NPB * SLOTS];   // 16 KB padded image
    int b = blockIdx.x;
    int t = threadIdx.x;
    int cnt = min(bcursor[b], CAP);
    const uint32_t* pb = pairs + (size_t)b * CAP;
    s_hist[t] = 0; s_cur[t] = 0;
    for (int i = t; i < NPB * SLOTS; i += 256) s_pad[i] = n;   // dummy fill
    __syncthreads();
    for (int i = t; i < cnt; i += 256)
        atomicAdd(&s_hist[__builtin_nontemporal_load(&pb[i]) >> 18], 1);
    __syncthreads();
    // exclusive scan of s_hist[256]
    int v = s_hist[t];
    s_tmp[t] = v;
    __syncthreads();
    for (int off = 1; off < 256; off <<= 1) {
        int u = (t >= off) ? s_tmp[t - off] : 0;
        __syncthreads();
        s_tmp[t] += u;
        __syncthreads();
    }
    s_start[t] = s_tmp[t] - v;
    __syncthreads();
    // meta + dis + xdh (1 node per thread, coalesced)
    int cb = b * CAP;                    // bucket-strided overflow base
    int node = (b << 8) + t;
    if (node < n) {
        int deg = s_hist[t];
        meta[node] = ((unsigned int)deg << 21) | (unsigned int)(cb + s_start[t]);
        float di = rsqrtf((float)(deg + 1));   // +1 self-loop
        dis[node] = di;
        const float4* xi = (const float4*)(x + (size_t)node * IN_DIM);
        float4 a = xi[0], c = xi[1];
        union { __half2 h[4]; int iv[4]; } u;
        u.h[0] = __float22half2_rn(make_float2(a.x * di, a.y * di));
        u.h[1] = __float22half2_rn(make_float2(a.z * di, a.w * di));
        u.h[2] = __float22half2_rn(make_float2(c.x * di, c.y * di));
        u.h[3] = __float22half2_rn(make_float2(c.z * di, c.w * di));
        ((int4*)xdh)[node] = make_int4(u.iv[0], u.iv[1], u.iv[2], u.iv[3]);
    } else if (node == n) {
        ((int4*)xdh)[n] = make_int4(0, 0, 0, 0);           // dummy zero row
    }
    __syncthreads();
    // place: first 16 per node into LDS pad; overflow -> bucket-strided csr_ovf (rare)
    for (int i = t; i < cnt; i += 256) {
        uint32_t p = __builtin_nontemporal_load(&pb[i]);
        int dl = p >> 18;
        int sidx = (int)(p & 0x3FFFFu);
        int pos = atomicAdd(&s_cur[dl], 1);
        if (pos < SLOTS) s_pad[dl * SLOTS + pos] = sidx;
        else             csr_ovf[cb + s_start[dl] + pos] = sidx;
    }
    __syncthreads();
    // coalesced int4 flush (guard phantom nodes past n)
    for (int i = t; i < NPB * SLOTS / 4; i += 256) {
        int node2 = (b << 8) + (i >> 2);
        if (node2 < n)
            ((int4*)csr_pad)[(size_t)(b << 8) * 4 + i] = ((int4*)s_pad)[i];
    }
}

// ---------------- agg1 + MLP fused: node per LANE (R12) ----------------
__global__ void __launch_bounds__(256) k_agg1f(
        const int* __restrict__ csr_pad, const int* __restrict__ csr_ovf,
        const unsigned int* __restrict__ meta, const __half2* __restrict__ xdh,
        const float* __restrict__ dis, const float* __restrict__ W1,
        const float* __restrict__ b1, const float* __restrict__ W2,
        __half2* __restrict__ y2h, int n) {
    __shared__ float sW1[IN_DIM * H1];
    __shared__ float sW2[H1 * H2];
    __shared__ float sb1[H1];
    for (int i = threadIdx.x; i < IN_DIM * H1; i += 256) sW1[i] = W1[i];
    for (int i = threadIdx.x; i < H1 * H2; i += 256) sW2[i] = W2[i];
    if (threadIdx.x < H1) sb1[threadIdx.x] = b1[threadIdx.x];
    __syncthreads();
    int node = blockIdx.x * 256 + threadIdx.x;
    if (node > n) return;
    int4* orow = (int4*)y2h + (size_t)node * 2;
    if (node == n) {                     // dummy zero row for agg2
        orow[0] = make_int4(0, 0, 0, 0);
        orow[1] = make_int4(0, 0, 0, 0);
        return;
    }
    const int4* pr = (const int4*)(csr_pad + (size_t)node * SLOTS);
    int4 p0 = pr[0], p1 = pr[1], p2 = pr[2], p3 = pr[3];
    unsigned int m = meta[node];
    const int4* xt = (const int4*)xdh;

    float acc[8] = {0, 0, 0, 0, 0, 0, 0, 0};
    int idx[16] = {p0.x, p0.y, p0.z, p0.w, p1.x, p1.y, p1.z, p1.w,
                   p2.x, p2.y, p2.z, p2.w, p3.x, p3.y, p3.z, p3.w};
    acc_row8(acc, xt[node]);             // self-loop
#pragma unroll
    for (int i = 0; i < 16; ++i) acc_row8(acc, xt[(size_t)idx[i]]);
    int deg = m >> 21;
    if (deg > SLOTS) {                   // rare overflow
        int r0 = (int)(m & 0x1FFFFF);
        for (int r = SLOTS; r < deg; ++r) acc_row8(acc, xt[(size_t)csr_ovf[r0 + r]]);
    }
    float di = dis[node];
    float z[8];
#pragma unroll
    for (int k = 0; k < 8; ++k) z[k] = acc[k] * di;

    float y2[H2];
#pragma unroll
    for (int j = 0; j < H2; ++j) y2[j] = 0.f;
    for (int d = 0; d < H1; ++d) {
        float h = sb1[d];
#pragma unroll
        for (int k = 0; k < 8; ++k) h = fmaf(z[k], sW1[k * H1 + d], h);
        h = fmaxf(h, 0.f);
#pragma unroll
        for (int j = 0; j < H2; ++j) y2[j] = fmaf(h, sW2[d * H2 + j], y2[j]);
    }
    union { __half2 h2v[8]; int iv[8]; } u;
#pragma unroll
    for (int q = 0; q < 6; ++q)
        u.h2v[q] = __float22half2_rn(make_float2(y2[2 * q] * di, y2[2 * q + 1] * di));
    u.h2v[6] = __float22half2_rn(make_float2(0.f, 0.f));
    u.h2v[7] = u.h2v[6];
    orow[0] = make_int4(u.iv[0], u.iv[1], u.iv[2], u.iv[3]);
    orow[1] = make_int4(u.iv[4], u.iv[5], u.iv[6], u.iv[7]);
}

// ---------------- layer-2 aggregation + FUSED segmented max-pool ----------------
// node per lane; after computing h2[12] in-register, wave-level segmented
// max-scan over batch-sorted nodes; one atomicMax burst per wave-segment.
__global__ void __launch_bounds__(256) k_agg2(
        const int* __restrict__ csr_pad, const int* __restrict__ csr_ovf,
        const unsigned int* __restrict__ meta, const __half2* __restrict__ y2h,
        const float* __restrict__ dis, const float* __restrict__ b2,
        const int* __restrict__ batch, unsigned int* __restrict__ pooled, int n) {
    int node = blockIdx.x * 256 + threadIdx.x;
    int lane = threadIdx.x & 63;
    bool active = node < n;
    float v[12] = {0, 0, 0, 0, 0, 0, 0, 0, 0, 0, 0, 0};
    int gid = 0x7fffffff;
    if (active) {
        const int4* pr = (const int4*)(csr_pad + (size_t)node * SLOTS);
        int4 p0 = pr[0], p1 = pr[1], p2 = pr[2], p3 = pr[3];
        unsigned int m = meta[node];
        const int4* yt = (const int4*)y2h;   // 32B rows = 2 int4
        float acc[12] = {0, 0, 0, 0, 0, 0, 0, 0, 0, 0, 0, 0};
        auto addrow = [&](int nb) {
            int4 ra = yt[(size_t)nb * 2];
            int4 rb = yt[(size_t)nb * 2 + 1];
            const __half2* ha = (const __half2*)&ra;
            const __half2* hb = (const __half2*)&rb;
#pragma unroll
            for (int q = 0; q < 4; ++q) {
                float2 f = __half22float2(ha[q]);
                acc[2 * q] += f.x; acc[2 * q + 1] += f.y;
            }
#pragma unroll
            for (int q = 0; q < 2; ++q) {
                float2 f = __half22float2(hb[q]);
                acc[8 + 2 * q] += f.x; acc[9 + 2 * q] += f.y;
            }
        };
        int idx[16] = {p0.x, p0.y, p0.z, p0.w, p1.x, p1.y, p1.z, p1.w,
                       p2.x, p2.y, p2.z, p2.w, p3.x, p3.y, p3.z, p3.w};
        addrow(node);                        // self-loop
#pragma unroll
        for (int i = 0; i < 16; ++i) addrow(idx[i]);
        int deg = m >> 21;
        if (deg > SLOTS) {                   // rare overflow
            int r0 = (int)(m & 0x1FFFFF);
            for (int r = SLOTS; r < deg; ++r) addrow(csr_ovf[r0 + r]);
        }
        float di = dis[node];
#pragma unroll
        for (int q = 0; q < 12; ++q) v[q] = fmaxf(fmaf(acc[q], di, b2[q]), 0.f);
        gid = batch[node];
    }
    // wave segmented inclusive max-scan (batch sorted => segments contiguous)
#pragma unroll
    for (int off = 1; off < 64; off <<= 1) {
        int g2 = __shfl_up(gid, off, 64);
        bool merge = (lane >= off) && (g2 == gid);
#pragma unroll
        for (int q = 0; q < 12; ++q) {
            float tv = __shfl_up(v[q], off, 64);
            if (merge) v[q] = fmaxf(v[q], tv);
        }
    }
    int gnext = __shfl_down(gid, 1, 64);
    bool last = (lane == 63) || (gnext != gid);
    if (last && gid != 0x7fffffff) {
        unsigned int* pp = pooled + (size_t)gid * 12;
#pragma unroll
        for (int q = 0; q < 12; ++q) atomicMax(&pp[q], __float_as_uint(v[q]));
    }
}

// ---------------- head: logits + log_softmax from pooled ----------------
__global__ void k_head(const unsigned int* __restrict__ pooled,
                       const float* __restrict__ Wl, const float* __restrict__ bl,
                       float* __restrict__ out, int g) {
    int i = blockIdx.x * 256 + threadIdx.x;
    if (i >= g) return;
    float l0 = bl[0], l1 = bl[1];
#pragma unroll
    for (int k = 0; k < H2; ++k) {
        float pv = __uint_as_float(pooled[(size_t)i * 12 + k]);
        l0 = fmaf(pv, Wl[k * 2 + 0], l0);
        l1 = fmaf(pv, Wl[k * 2 + 1], l1);
    }
    float m = fmaxf(l0, l1);
    float lse = m + logf(expf(l0 - m) + expf(l1 - m));
    out[i * 2 + 0] = l0 - lse;
    out[i * 2 + 1] = l1 - lse;
}

extern "C" void kernel_launch(void* const* d_in, const int* in_sizes, int n_in,
                              void* d_out, int out_size, void* d_ws, size_t ws_size,
                              hipStream_t stream) {
    const float* x   = (const float*)d_in[0];
    const int* ei    = (const int*)d_in[1];
    const int* batch = (const int*)d_in[2];
    const float* W1  = (const float*)d_in[3];
    const float* b1  = (const float*)d_in[4];
    const float* W2  = (const float*)d_in[5];
    const float* b2  = (const float*)d_in[6];
    const float* Wl  = (const float*)d_in[7];
    const float* bl  = (const float*)d_in[8];
    float* out = (float*)d_out;

    const int N = in_sizes[0] / IN_DIM;   // 200000
    const int E = in_sizes[1] / 2;        // 1600000
    const int G = out_size / 2;           // 2000
    const int* src = ei;
    const int* dst = ei + E;

    auto cdiv = [](long long a, int b) { return (int)((a + b - 1) / b); };

    // workspace carve, 64B-aligned (bcursor+pooled first: single zeroing memset)
    char* wp = (char*)d_ws;
    auto carve = [&](size_t bytes) {
        char* p = wp;
        wp += (bytes + 63) & ~(size_t)63;
        return p;
    };
    int*          bcursor = (int*)carve(NBK * 4);
    unsigned int* pooled  = (unsigned int*)carve((size_t)G * H2 * 4);
    unsigned int* meta    = (unsigned int*)carve((size_t)N * 4);
    float*        dis     = (float*)carve((size_t)N * 4);
    __half2*      xdh     = (__half2*)carve((size_t)(N + 1) * 16);   // 16B rows
    __half2*      y2h     = (__half2*)carve((size_t)(N + 1) * 32);   // 32B rows
    uint32_t*     pairs   = (uint32_t*)carve((size_t)NBK * CAP * 4);
    int*          csr_pad = (int*)carve((size_t)N * SLOTS * 4);
    int*          csr_ovf = (int*)carve((size_t)NBK * CAP * 4);

    size_t zspan = (char*)(pooled + (size_t)G * H2) - (char*)bcursor;
    (void)hipMemsetAsync(bcursor, 0, zspan, stream);

    // CSR build (bucket-sorted binA -> padded csr in binB, fused meta/dis/xdh)
    k_binA<<<cdiv(E, CHUNK), 256, 0, stream>>>(src, dst, pairs, bcursor, E);
    k_binB<<<NBK, 256, 0, stream>>>(pairs, bcursor, x, csr_pad, csr_ovf,
                                    meta, dis, xdh, N);

    // fused layer-1 agg + MLP, layer-2 agg + fused pool, head
    k_agg1f<<<cdiv((long long)N + 1, 256), 256, 0, stream>>>(
        csr_pad, csr_ovf, meta, xdh, dis, W1, b1, W2, y2h, N);
    k_agg2<<<cdiv(N, 256), 256, 0, stream>>>(csr_pad, csr_ovf, meta, y2h, dis, b2,
                                             batch, pooled, N);
    k_head<<<cdiv(G, 256), 256, 0, stream>>>(pooled, Wl, bl, out, G);
}